// Round 5
// baseline (109.915 us; speedup 1.0000x reference)
//
#include <hip/hip_runtime.h>

// WTA_layer_Neuron: x [T=36, B=32, H=64, N=1024] f32 -> spikes (same shape).
// R4: one 256-thread BLOCK per (b,h) pair (4 waves/pair), 4 neurons/thread.
// 2048 blocks = 8192 waves = 32 waves/CU (full occupancy) vs R2's 8.
// Cross-wave max combine via 4-slot LDS + 1 barrier/step (parity ping-pong).
// Distance-1 register prefetch + non-temporal loads/stores retained from R2.

constexpr int T_TOTAL = 36;
constexpr int T_FIRE0 = 12;          // START + WAIT
constexpr int NPAIR   = 32 * 64;     // B * H = 2048
constexpr int NN      = 1024;        // neurons per pair

using f32x4 = __attribute__((ext_vector_type(4))) float;

template <bool FIRE>
__device__ __forceinline__ void process_step(const f32x4 xa, float (&v)[4],
                                             unsigned& blockmask, float& bi, float& th,
                                             float* __restrict__ ot, int wid, int lane,
                                             int par, float (*smax)[4]) {
    // wave-local max over this thread's 4 neurons, then wave reduce
    float mw = fmaxf(fmaxf(xa[0], xa[1]), fmaxf(xa[2], xa[3]));
#pragma unroll
    for (int off = 32; off >= 1; off >>= 1)
        mw = fmaxf(mw, __shfl_xor(mw, off, 64));
    if (lane == 0) smax[par][wid] = mw;
    __syncthreads();
    const float m = fmaxf(fmaxf(smax[par][0], smax[par][1]),
                          fmaxf(smax[par][2], smax[par][3]));

    const float sub = m * bi;                 // exact: bi in {0,1}
    if (!FIRE) {
#pragma unroll
        for (int j = 0; j < 4; ++j)
            v[j] += xa[j] - sub;
        const f32x4 z = {0.f, 0.f, 0.f, 0.f};
        __builtin_nontemporal_store(z, (f32x4*)ot);
    } else {
        f32x4 ov;
#pragma unroll
        for (int j = 0; j < 4; ++j) {
            float vn = v[j] + (xa[j] - sub);     // v = v + xt
            const bool spike = (vn >= th);       // fire check
            v[j] = spike ? (vn - th) : vn;       // soft reset (even if blocked)
            const bool blocked = (blockmask >> j) & 1u;
            ov[j] = (spike && !blocked) ? 1.0f : 0.0f;
            if (spike) blockmask |= (1u << j);
        }
        __builtin_nontemporal_store(ov, (f32x4*)ot);
        th *= 0.5f;                              // th /= tau (exact)
    }
    if (m > 0.0f) bi = 0.0f;
}

__global__ __launch_bounds__(256, 8) void wta_kernel(const float* __restrict__ x,
                                                     float* __restrict__ out) {
    const int pair = blockIdx.x;
    const int tid  = threadIdx.x;
    const int wid  = tid >> 6;
    const int lane = tid & 63;
    const size_t base = (size_t)pair * NN + 4 * (size_t)tid;
    const size_t stride = (size_t)NPAIR * NN;    // per-timestep stride

    __shared__ float smax[2][4];

    float v[4] = {0.f, 0.f, 0.f, 0.f};
    unsigned blockmask = 0;                      // bits 0..3: this thread's neurons
    float bi = 1.0f;                             // block_input (block-uniform)

    // V_TH0 = 2^23 / (1/ln 2) / 2, f64 exactly as numpy does.
    const double ln2 = 0.6931471805599453;
    float th = (float)(8388608.0 / (1.0 / ln2) / 2.0);

    const float* xp = x + base;
    float* op = out + base;

    f32x4 A = __builtin_nontemporal_load((const f32x4*)(xp));          // t = 0
    f32x4 B;

    // ---- Phase 1: t in [0,12), 2-unrolled, prefetch distance 1 ----
    for (int t = 0; t < T_FIRE0; t += 2) {
        B = __builtin_nontemporal_load((const f32x4*)(xp + (size_t)(t + 1) * stride));
        process_step<false>(A, v, blockmask, bi, th, op + (size_t)t * stride,
                            wid, lane, t & 1, smax);
        A = __builtin_nontemporal_load((const f32x4*)(xp + (size_t)(t + 2) * stride));
        process_step<false>(B, v, blockmask, bi, th, op + (size_t)(t + 1) * stride,
                            wid, lane, (t + 1) & 1, smax);
    }

    // ---- Phase 2: t in [12,34), A holds t=12 ----
    for (int t = T_FIRE0; t < T_TOTAL - 2; t += 2) {
        B = __builtin_nontemporal_load((const f32x4*)(xp + (size_t)(t + 1) * stride));
        process_step<true>(A, v, blockmask, bi, th, op + (size_t)t * stride,
                           wid, lane, t & 1, smax);
        A = __builtin_nontemporal_load((const f32x4*)(xp + (size_t)(t + 2) * stride));
        process_step<true>(B, v, blockmask, bi, th, op + (size_t)(t + 1) * stride,
                           wid, lane, (t + 1) & 1, smax);
    }
    // ---- tail: t = 34, 35 (A holds t=34) ----
    {
        const int t = T_TOTAL - 2;
        B = __builtin_nontemporal_load((const f32x4*)(xp + (size_t)(t + 1) * stride));
        process_step<true>(A, v, blockmask, bi, th, op + (size_t)t * stride,
                           wid, lane, t & 1, smax);
        process_step<true>(B, v, blockmask, bi, th, op + (size_t)(t + 1) * stride,
                           wid, lane, (t + 1) & 1, smax);
    }
}

extern "C" void kernel_launch(void* const* d_in, const int* in_sizes, int n_in,
                              void* d_out, int out_size, void* d_ws, size_t ws_size,
                              hipStream_t stream) {
    const float* x = (const float*)d_in[0];
    float* out = (float*)d_out;
    // one block per (b,h) pair
    wta_kernel<<<dim3(NPAIR), dim3(256), 0, stream>>>(x, out);
}

// Round 6
// 96.983 us; speedup vs baseline: 1.1333x; 1.1333x over previous
//
#include <hip/hip_runtime.h>

// WTA_layer_Neuron: x [T=36, B=32, H=64, N=1024] f32 -> spikes (same shape).
// One wave (64 lanes) per (b,h) pair: 2048 pairs, 16 neurons/lane.
// R5: R2 structure (distance-1 register prefetch, NT loads) but stores go
// through L2 (no NT) -- let L2 aggregate dirty lines into large DRAM bursts
// like the 6.9 TB/s fillBuffer does, instead of 2048 fine-grained NT write
// streams interleaved with reads.

constexpr int T_TOTAL = 36;
constexpr int T_FIRE0 = 12;          // START + WAIT
constexpr int NPAIR   = 32 * 64;     // B * H = 2048
constexpr int NN      = 1024;        // neurons per pair

using f32x4 = __attribute__((ext_vector_type(4))) float;

__device__ __forceinline__ void load4(f32x4 (&xa)[4], const float* __restrict__ xt, int lane) {
#pragma unroll
    for (int k = 0; k < 4; ++k)
        xa[k] = __builtin_nontemporal_load((const f32x4*)(xt + 4 * lane + 256 * k));
}

template <bool FIRE>
__device__ __forceinline__ void process_step(const f32x4 (&xa)[4], float (&v)[16],
                                             unsigned& blockmask, float& bi, float& th,
                                             float* __restrict__ ot, int lane) {
    // wave max over this pair's 1024 elements
    float m = xa[0][0];
#pragma unroll
    for (int k = 0; k < 4; ++k)
        m = fmaxf(m, fmaxf(fmaxf(xa[k][0], xa[k][1]), fmaxf(xa[k][2], xa[k][3])));
#pragma unroll
    for (int off = 32; off >= 1; off >>= 1)
        m = fmaxf(m, __shfl_xor(m, off, 64));

    const float sub = m * bi;                 // exact: bi in {0,1}
    if (!FIRE) {
        // charge-only: v += xt - sub, output all zeros
#pragma unroll
        for (int k = 0; k < 4; ++k) {
#pragma unroll
            for (int j = 0; j < 4; ++j)
                v[4 * k + j] += xa[k][j] - sub;
        }
        const f32x4 z = {0.f, 0.f, 0.f, 0.f};
#pragma unroll
        for (int k = 0; k < 4; ++k)
            *(f32x4*)(ot + 4 * lane + 256 * k) = z;            // cached store
    } else {
#pragma unroll
        for (int k = 0; k < 4; ++k) {
            f32x4 ov;
#pragma unroll
            for (int j = 0; j < 4; ++j) {
                const int idx = 4 * k + j;
                float vn = v[idx] + (xa[k][j] - sub);   // v = v + xt
                const bool spike = (vn >= th);          // fire check
                v[idx] = spike ? (vn - th) : vn;        // soft reset (even if blocked)
                const bool blocked = (blockmask >> idx) & 1u;
                ov[j] = (spike && !blocked) ? 1.0f : 0.0f;
                if (spike) blockmask |= (1u << idx);
            }
            *(f32x4*)(ot + 4 * lane + 256 * k) = ov;           // cached store
        }
        th *= 0.5f;                                     // th /= tau (exact)
    }
    if (m > 0.0f) bi = 0.0f;
}

__global__ __launch_bounds__(256) void wta_kernel(const float* __restrict__ x,
                                                  float* __restrict__ out) {
    const int gtid = blockIdx.x * 256 + threadIdx.x;
    const int pair = gtid >> 6;                  // wave id = (b,h) pair
    const int lane = threadIdx.x & 63;
    const size_t pair_off = (size_t)pair * NN;

    float v[16];
#pragma unroll
    for (int i = 0; i < 16; ++i) v[i] = 0.0f;
    unsigned blockmask = 0;
    float bi = 1.0f;                             // block_input (wave-uniform)

    // V_TH0 = 2^23 / (1/ln 2) / 2, f64 exactly as numpy does.
    const double ln2 = 0.6931471805599453;
    float th = (float)(8388608.0 / (1.0 / ln2) / 2.0);

    const float* xb = x + pair_off;
    float* ob = out + pair_off;
    const size_t stride = (size_t)NPAIR * NN;    // per-timestep stride

    f32x4 A[4], B[4];
    load4(A, xb, lane);                          // t = 0

    // ---- Phase 1: t in [0,12), 2-unrolled with prefetch ----
    for (int t = 0; t < T_FIRE0; t += 2) {
        load4(B, xb + (size_t)(t + 1) * stride, lane);
        process_step<false>(A, v, blockmask, bi, th, ob + (size_t)t * stride, lane);
        load4(A, xb + (size_t)(t + 2) * stride, lane);   // t+2 <= 13 < 36, always valid
        process_step<false>(B, v, blockmask, bi, th, ob + (size_t)(t + 1) * stride, lane);
    }

    // ---- Phase 2: t in [12,34), A already holds t=12 ----
    for (int t = T_FIRE0; t < T_TOTAL - 2; t += 2) {
        load4(B, xb + (size_t)(t + 1) * stride, lane);
        process_step<true>(A, v, blockmask, bi, th, ob + (size_t)t * stride, lane);
        load4(A, xb + (size_t)(t + 2) * stride, lane);
        process_step<true>(B, v, blockmask, bi, th, ob + (size_t)(t + 1) * stride, lane);
    }
    // ---- tail: t = 34, 35 ----
    {
        const int t = T_TOTAL - 2;
        load4(B, xb + (size_t)(t + 1) * stride, lane);
        process_step<true>(A, v, blockmask, bi, th, ob + (size_t)t * stride, lane);
        process_step<true>(B, v, blockmask, bi, th, ob + (size_t)(t + 1) * stride, lane);
    }
}

extern "C" void kernel_launch(void* const* d_in, const int* in_sizes, int n_in,
                              void* d_out, int out_size, void* d_ws, size_t ws_size,
                              hipStream_t stream) {
    const float* x = (const float*)d_in[0];
    float* out = (float*)d_out;
    // 2048 waves, 4 waves per 256-thread block -> 512 blocks
    wta_kernel<<<dim3(NPAIR / 4), dim3(256), 0, stream>>>(x, out);
}